// Round 2
// baseline (685.694 us; speedup 1.0000x reference)
//
#include <hip/hip_runtime.h>

// CBAM attention, fp32 in/out. B=32, C=512, Cr=64, H=W=64, HW=4096.
// Pipeline: [pool over HW] -> [spectral norms] -> [MLP -> s] ->
//           [x*s, pool over C -> ca/cm] -> [3x3 conv -> y; out = x*s*sig(y)]

#define B_   32
#define C_   512
#define CR_  64
#define HW_  4096
#define WID_ 64
#define EPSF 1e-12f

__device__ __forceinline__ float sigmoidf(float x) {
  return 1.0f / (1.0f + __expf(-x));
}

// ---------------- K1: avg/max over HW per (b,c) plane ----------------
__global__ __launch_bounds__(256) void pool_kernel(const float* __restrict__ x,
                                                   float* __restrict__ avg,
                                                   float* __restrict__ mx) {
  const int plane = blockIdx.x;           // b*C + c: 4096 contiguous floats
  const int t = threadIdx.x;
  const float4* xp = (const float4*)(x + (size_t)plane * HW_);
  float s = 0.0f, m = -INFINITY;
  #pragma unroll
  for (int q = 0; q < 4; q++) {
    float4 a = xp[q * 256 + t];
    s += (a.x + a.y) + (a.z + a.w);
    m = fmaxf(m, fmaxf(fmaxf(a.x, a.y), fmaxf(a.z, a.w)));
  }
  for (int o = 32; o > 0; o >>= 1) {
    s += __shfl_down(s, o);
    m = fmaxf(m, __shfl_down(m, o));
  }
  __shared__ float rs[4], rm[4];
  int wave = t >> 6, lane = t & 63;
  if (lane == 0) { rs[wave] = s; rm[wave] = m; }
  __syncthreads();
  if (t == 0) {
    float S = rs[0] + rs[1] + rs[2] + rs[3];
    float M = fmaxf(fmaxf(rm[0], rm[1]), fmaxf(rm[2], rm[3]));
    avg[plane] = S * (1.0f / HW_);
    mx[plane] = M;
  }
}

// ---------------- K2: spectral norms (sv1, sv2, sv3) ----------------
__device__ __forceinline__ float block_reduce_sum(float v, float* red) {
  int t = threadIdx.x;
  red[t] = v;
  __syncthreads();
  for (int o = 128; o > 0; o >>= 1) {
    if (t < o) red[t] += red[t + o];
    __syncthreads();
  }
  float r = red[0];
  __syncthreads();
  return r;
}

__global__ __launch_bounds__(256) void sv_kernel(const float* __restrict__ w1, const float* __restrict__ u1,
                                                 const float* __restrict__ w2, const float* __restrict__ u2,
                                                 const float* __restrict__ w3, const float* __restrict__ u3,
                                                 float* __restrict__ sv) {
  __shared__ float v[C_];
  __shared__ float red[256];
  const int t = threadIdx.x;

  // ---- sv1: W1m = [CR_=64, C_=512] ----
  for (int j = t; j < C_; j += 256) {
    float a = 0.0f;
    for (int i = 0; i < CR_; i++) a += u1[i] * w1[i * C_ + j];
    v[j] = a;
  }
  __syncthreads();
  float p = 0.0f;
  for (int j = t; j < C_; j += 256) p += v[j] * v[j];
  float nv = block_reduce_sum(p, red);
  float dv = fmaxf(sqrtf(nv), EPSF);
  float q = 0.0f;
  if (t < CR_) {
    float a = 0.0f;
    for (int j = 0; j < C_; j++) a += v[j] * w1[t * C_ + j];
    a /= dv;
    q = a * a;
  }
  float nt2 = block_reduce_sum(q, red);
  if (t == 0) sv[0] = nt2 / fmaxf(sqrtf(nt2), EPSF);
  __syncthreads();

  // ---- sv2: W2m = [C_=512, CR_=64] ----
  if (t < CR_) {
    float a = 0.0f;
    for (int i = 0; i < C_; i++) a += u2[i] * w2[i * CR_ + t];
    v[t] = a;
  }
  __syncthreads();
  p = (t < CR_) ? v[t] * v[t] : 0.0f;
  nv = block_reduce_sum(p, red);
  dv = fmaxf(sqrtf(nv), EPSF);
  q = 0.0f;
  for (int i = t; i < C_; i += 256) {
    float a = 0.0f;
    for (int j = 0; j < CR_; j++) a += v[j] * w2[i * CR_ + j];
    a /= dv;
    q += a * a;
  }
  nt2 = block_reduce_sum(q, red);
  if (t == 0) sv[1] = nt2 / fmaxf(sqrtf(nt2), EPSF);

  // ---- sv3: W3m = [1, 18] ----
  if (t == 0) {
    float u3v = u3[0];
    float nvs = 0.0f;
    for (int k = 0; k < 18; k++) { float vv = u3v * w3[k]; nvs += vv * vv; }
    float d = fmaxf(sqrtf(nvs), EPSF);
    float tt = 0.0f;
    for (int k = 0; k < 18; k++) tt += (u3v * w3[k] / d) * w3[k];
    float u2n = tt / fmaxf(fabsf(tt), EPSF);
    sv[2] = tt * u2n;
  }
}

// ---------------- K3: MLP -> s[B,C] ----------------
__global__ __launch_bounds__(256) void mlp_kernel(const float* __restrict__ avg, const float* __restrict__ mx,
                                                  const float* __restrict__ w1, const float* __restrict__ b1,
                                                  const float* __restrict__ w2, const float* __restrict__ b2,
                                                  const float* __restrict__ sv, float* __restrict__ s) {
  const int b = blockIdx.x;
  const int t = threadIdx.x;
  __shared__ float pool[2][C_];
  __shared__ float hid[2][CR_];
  for (int i = t; i < C_; i += 256) {
    pool[0][i] = avg[b * C_ + i];
    pool[1][i] = mx[b * C_ + i];
  }
  __syncthreads();
  const float inv1 = 1.0f / sv[0];
  const float inv2 = 1.0f / sv[1];
  if (t < 2 * CR_) {
    int kind = t >> 6;      // 0 = avg, 1 = max
    int i = t & 63;
    const float4* wr = (const float4*)(w1 + (size_t)i * C_);
    float acc = 0.0f;
    for (int qq = 0; qq < C_ / 4; qq++) {
      float4 u = wr[qq];
      acc += pool[kind][qq * 4 + 0] * u.x + pool[kind][qq * 4 + 1] * u.y +
             pool[kind][qq * 4 + 2] * u.z + pool[kind][qq * 4 + 3] * u.w;
    }
    hid[kind][i] = fmaxf(acc * inv1 + b1[i], 0.0f);
  }
  __syncthreads();
  for (int c = t; c < C_; c += 256) {
    const float* wr = w2 + (size_t)c * CR_;
    float aa = 0.0f, mm = 0.0f;
    #pragma unroll 8
    for (int i = 0; i < CR_; i++) {
      float wv = wr[i];
      aa += hid[0][i] * wv;
      mm += hid[1][i] * wv;
    }
    float val = (aa + mm) * inv2 + 2.0f * b2[c];
    s[b * C_ + c] = sigmoidf(val);
  }
}

// ---------------- K4: x*s, mean/max over C -> ca, cm ----------------
__global__ __launch_bounds__(256) void scale_pool_kernel(const float* __restrict__ x,
                                                         const float* __restrict__ s,
                                                         float* __restrict__ ca,
                                                         float* __restrict__ cm) {
  const int b = blockIdx.y;
  const int hw0 = blockIdx.x * 512;
  const int t = threadIdx.x;
  __shared__ float srow[C_];
  for (int i = t; i < C_; i += 256) srow[i] = s[b * C_ + i];
  __syncthreads();
  const int px = hw0 + t * 2;
  const float* xb = x + (size_t)b * C_ * HW_ + px;
  float s0 = 0.f, s1 = 0.f, m0 = -INFINITY, m1 = -INFINITY;
  #pragma unroll 8
  for (int c = 0; c < C_; c++) {
    float2 u = *(const float2*)(xb + (size_t)c * HW_);
    float sc = srow[c];
    float v0 = u.x * sc, v1 = u.y * sc;
    s0 += v0; s1 += v1;
    m0 = fmaxf(m0, v0); m1 = fmaxf(m1, v1);
  }
  *(float2*)(ca + b * HW_ + px) = make_float2(s0 * (1.0f / C_), s1 * (1.0f / C_));
  *(float2*)(cm + b * HW_ + px) = make_float2(m0, m1);
}

// ---------------- K5: 3x3 conv -> y; out = x*s*sigmoid(y) ----------------
__global__ __launch_bounds__(256) void conv_out_kernel(const float* __restrict__ x,
                                                       const float* __restrict__ s,
                                                       const float* __restrict__ ca,
                                                       const float* __restrict__ cm,
                                                       const float* __restrict__ w3,
                                                       const float* __restrict__ b3,
                                                       const float* __restrict__ sv,
                                                       float* __restrict__ out) {
  const int b = blockIdx.y;
  const int hw0 = blockIdx.x * 512;
  const int t = threadIdx.x;
  __shared__ float srow[C_];
  for (int i = t; i < C_; i += 256) srow[i] = s[b * C_ + i];
  __syncthreads();
  const float inv3 = 1.0f / sv[2];
  float wn[18];
  #pragma unroll
  for (int k = 0; k < 18; k++) wn[k] = w3[k] * inv3;
  const float b3f = b3[0];

  float sy[2];
  #pragma unroll
  for (int e = 0; e < 2; e++) {
    int px = hw0 + t * 2 + e;
    int h = px >> 6, w = px & 63;
    float acc = b3f;
    #pragma unroll
    for (int dh = -1; dh <= 1; dh++) {
      int hh = h + dh;
      if (hh < 0 || hh >= 64) continue;
      #pragma unroll
      for (int dw = -1; dw <= 1; dw++) {
        int ww = w + dw;
        if (ww < 0 || ww >= WID_) continue;
        int n = b * HW_ + hh * WID_ + ww;
        int k = (dh + 1) * 3 + (dw + 1);
        acc += ca[n] * wn[k] + cm[n] * wn[9 + k];
      }
    }
    sy[e] = sigmoidf(acc);
  }

  const int px = hw0 + t * 2;
  const float* xb = x + (size_t)b * C_ * HW_ + px;
  float* ob = out + (size_t)b * C_ * HW_ + px;
  #pragma unroll 8
  for (int c = 0; c < C_; c++) {
    float2 u = *(const float2*)(xb + (size_t)c * HW_);
    float sc = srow[c];
    *(float2*)(ob + (size_t)c * HW_) = make_float2(u.x * sc * sy[0], u.y * sc * sy[1]);
  }
}

extern "C" void kernel_launch(void* const* d_in, const int* in_sizes, int n_in,
                              void* d_out, int out_size, void* d_ws, size_t ws_size,
                              hipStream_t stream) {
  const float* x  = (const float*)d_in[0];
  const float* w1 = (const float*)d_in[1];
  const float* b1 = (const float*)d_in[2];
  const float* u1 = (const float*)d_in[3];
  const float* w2 = (const float*)d_in[4];
  const float* b2 = (const float*)d_in[5];
  const float* u2 = (const float*)d_in[6];
  const float* w3 = (const float*)d_in[7];
  const float* b3 = (const float*)d_in[8];
  const float* u3 = (const float*)d_in[9];

  float* ws = (float*)d_ws;
  float* avg = ws;                    // 16384 floats
  float* mx  = ws + 16384;            // 16384
  float* s   = ws + 32768;            // 16384
  float* sv  = ws + 49152;            // 4 (padded to 16384)
  float* ca  = ws + 65536;            // 131072
  float* cm  = ws + 196608;           // 131072   (total 1.25 MiB)

  pool_kernel<<<B_ * C_, 256, 0, stream>>>(x, avg, mx);
  sv_kernel<<<1, 256, 0, stream>>>(w1, u1, w2, u2, w3, u3, sv);
  mlp_kernel<<<B_, 256, 0, stream>>>(avg, mx, w1, b1, w2, b2, sv, s);
  scale_pool_kernel<<<dim3(8, B_), 256, 0, stream>>>(x, s, ca, cm);
  conv_out_kernel<<<dim3(8, B_), 256, 0, stream>>>(x, s, ca, cm, w3, b3, sv, (float*)d_out);
}